// Round 1
// baseline (942.013 us; speedup 1.0000x reference)
//
#include <hip/hip_runtime.h>

// BilinearUpSampling3D: (2,96,96,48,32) f32 -> (2,192,192,96,32) f32.
// TF v1 align_corners=False with exactly 2x per axis => even out idx = copy,
// odd out idx = 0.5*(in[i] + in[min(i+1, n-1)]). Separable, weights exact.
//
// One thread = one float4 channel chunk of a 2x2x2 output voxel block:
// 8 float4 loads -> 8 float4 stores. Lane order (c4 fastest, then k) makes a
// wave's loads a contiguous 1KB and every store an aligned full 128B segment.
//
// R1 change: all 8 output stores are NONTEMPORAL (`nt` cache policy).
// Output (906 MB) is write-once; without nt it streams through L2+L3 and
// evicts the 113 MB input, forcing the 8x-redundant neighbor reads (dj/di
// are consumed by other blocks) out to HBM. nt keeps the input L3-resident.

typedef float v4f __attribute__((ext_vector_type(4)));

// Input strides in float4 units: c4:1, k:8, j:384, i:36864, b:3538944
// Output strides in float4 units: c4:1, d:8, w:768, h:147456, b:28311552
__global__ __launch_bounds__(256) void upsample2x_kernel(
    const v4f* __restrict__ in, v4f* __restrict__ out) {
    const int tid = blockIdx.x * 256 + threadIdx.x;  // grid sized exactly
    const int c4 = tid & 7;
    int t = tid >> 3;
    const int k = t % 48; t /= 48;
    const int j = t % 96; t /= 96;
    const int i = t % 96;
    const int b = t / 96;

    // clamped neighbor offsets (0 at the edge -> reload same element)
    const int dk = (k < 47) ? 8 : 0;
    const int dj = (j < 95) ? 384 : 0;
    const int di = (i < 95) ? 36864 : 0;

    const v4f* p = in + (size_t)b * 3538944 + i * 36864 + j * 384 + k * 8 + c4;
    const v4f c000 = p[0];
    const v4f c001 = p[dk];
    const v4f c010 = p[dj];
    const v4f c011 = p[dj + dk];
    const v4f c100 = p[di];
    const v4f c101 = p[di + dk];
    const v4f c110 = p[di + dj];
    const v4f c111 = p[di + dj + dk];

    const v4f s00 = c000 + c001;  // h0 w0, d-pair sum
    const v4f s01 = c010 + c011;  // h0 w1
    const v4f s10 = c100 + c101;  // h1 w0
    const v4f s11 = c110 + c111;  // h1 w1

    v4f* q = out + (size_t)b * 28311552 + i * 294912 + j * 1536 + k * 16 + c4;
    // h = 2i, w = 2j
    __builtin_nontemporal_store(c000,                                  q + 0);
    __builtin_nontemporal_store(s00 * 0.5f,                            q + 8);
    __builtin_nontemporal_store((c000 + c010) * 0.5f,                  q + 768);
    __builtin_nontemporal_store((s00 + s01) * 0.25f,                   q + 776);
    // h = 2i+1
    __builtin_nontemporal_store((c000 + c100) * 0.5f,                  q + 147456);
    __builtin_nontemporal_store((s00 + s10) * 0.25f,                   q + 147464);
    __builtin_nontemporal_store(((c000 + c010) + (c100 + c110)) * 0.25f, q + 148224);
    __builtin_nontemporal_store(((s00 + s01) + (s10 + s11)) * 0.125f,  q + 148232);
}

extern "C" void kernel_launch(void* const* d_in, const int* in_sizes, int n_in,
                              void* d_out, int out_size, void* d_ws, size_t ws_size,
                              hipStream_t stream) {
    const v4f* in = (const v4f*)d_in[0];
    v4f* out = (v4f*)d_out;
    // total threads = 2*96*96*48*8 = 7,077,888 = 27648 blocks * 256
    upsample2x_kernel<<<27648, 256, 0, stream>>>(in, out);
}